// Round 14
// baseline (677.817 us; speedup 1.0000x reference)
//
#include <hip/hip_runtime.h>
#include <hip/hip_bf16.h>

typedef short short8 __attribute__((ext_vector_type(8)));
typedef float f32x4 __attribute__((ext_vector_type(4)));
typedef int int4v __attribute__((ext_vector_type(4)));

#define B_ 2
#define S_ 2048
#define D_ 2048
#define H_ 16
#define HD_ 128
#define K_ 2048   // GEMM K (both projections)

#define GLL16(gp, lp) __builtin_amdgcn_global_load_lds( \
    (const __attribute__((address_space(1))) void*)(gp), \
    (__attribute__((address_space(3))) void*)(lp), 16, 0, 0)

__device__ inline ushort f2bf(float f) {
    union { float f; unsigned u; } v; v.f = f;
    unsigned r = v.u + 0x7FFFu + ((v.u >> 16) & 1u);
    return (ushort)(r >> 16);
}
__device__ inline float bf2f(ushort b) {
    union { unsigned u; float f; } v; v.u = ((unsigned)b) << 16;
    return v.f;
}

// rope 4 (even,odd) bf16 pairs in-register; cosp/sinp point at 4 consecutive f32
__device__ inline short8 rope8(short8 raw, const float* __restrict__ cosp,
                               const float* __restrict__ sinp) {
    float4 cs = *reinterpret_cast<const float4*>(cosp);
    float4 sn = *reinterpret_cast<const float4*>(sinp);
    const float* c = reinterpret_cast<const float*>(&cs);
    const float* s = reinterpret_cast<const float*>(&sn);
    short8 out;
    #pragma unroll
    for (int j = 0; j < 4; ++j) {
        float a = bf2f((ushort)raw[2 * j]), b = bf2f((ushort)raw[2 * j + 1]);
        out[2 * j]     = (short)f2bf(fmaf(a, c[j], -(b * s[j])));
        out[2 * j + 1] = (short)f2bf(fmaf(a, s[j], b * c[j]));
    }
    return out;
}

// z=0..3: w[K][N] f32 -> wT[N][K] bf16 via 64x64 LDS tile.
// z=4..5: fp32->bf16 cast of x (4 float4 chunks per block, stride 524288).
__global__ __launch_bounds__(256) void prep_kernel(
        const float* __restrict__ s0, const float* __restrict__ s1,
        const float* __restrict__ s2, const float* __restrict__ s3,
        ushort* __restrict__ d0, ushort* __restrict__ d1,
        ushort* __restrict__ d2, ushort* __restrict__ d3,
        const float* __restrict__ x, ushort* __restrict__ xb) {
    const int z = blockIdx.z;
    const int t = threadIdx.x;
    if (z >= 4) {
        const int lane = (((z - 4) * 1024 + blockIdx.y * 32 + blockIdx.x) << 8) + t;
        #pragma unroll
        for (int k = 0; k < 4; ++k) {
            int i = lane + k * 524288;
            float4 v = reinterpret_cast<const float4*>(x)[i];
            ushort4 o;
            o.x = f2bf(v.x); o.y = f2bf(v.y); o.z = f2bf(v.z); o.w = f2bf(v.w);
            reinterpret_cast<ushort4*>(xb)[i] = o;
        }
        return;
    }
    __shared__ ushort tile[64][72];
    const float* src = (z == 0) ? s0 : (z == 1) ? s1 : (z == 2) ? s2 : s3;
    ushort* dst = (z == 0) ? d0 : (z == 1) ? d1 : (z == 2) ? d2 : d3;
    const int bk = blockIdx.y * 64, bn = blockIdx.x * 64;
    #pragma unroll
    for (int it = 0; it < 4; ++it) {
        int id = t + it * 256;
        int row = id >> 4;
        int c4 = (id & 15) * 4;
        float4 v = *reinterpret_cast<const float4*>(&src[(size_t)(bk + row) * D_ + bn + c4]);
        ushort4 o; o.x = f2bf(v.x); o.y = f2bf(v.y); o.z = f2bf(v.z); o.w = f2bf(v.w);
        *reinterpret_cast<ushort4*>(&tile[row][c4]) = o;
    }
    __syncthreads();
    #pragma unroll
    for (int it = 0; it < 4; ++it) {
        int id = t + it * 256;
        int n = id >> 4;
        int c4 = (id & 15) * 4;
        ushort4 o;
        o.x = tile[c4 + 0][n]; o.y = tile[c4 + 1][n];
        o.z = tile[c4 + 2][n]; o.w = tile[c4 + 3][n];
        *reinterpret_cast<ushort4*>(&dst[(size_t)(bn + n) * D_ + bk + c4]) = o;
    }
}

#define BAR8() __builtin_amdgcn_s_barrier()
#define VMC0() asm volatile("s_waitcnt vmcnt(0)" ::: "memory")
#define VMC8() asm volatile("s_waitcnt vmcnt(8)" ::: "memory")

// ========== QKV GEMM: 256x384 tile, 12 waves (2x6), per-wave 128x64, BK=64 ==========
// grid 16x16 = 256 = exactly one full round at 1 block/CU (160KB LDS), 3 waves/SIMD.
// Role-split staging: waves 0-3 stage A chunks (64 rows each), waves 4-9 stage B
// chunks, waves 10-11 none. 8 gloads/wave/tile. Ledger (verified per phase):
//   A: stage P1(t1)->buf1 / P5(s0)->buf0; wait vmcnt(0) at P4/P8 (3-phase lead)
//   B: stage P4(s0)->buf0 / P8(s1)->buf1; wait vmcnt(8) at P4/P8 (5-phase lead)
// All stage targets' last reads complete >=1 barrier before the stage issues.
// RoPE fused in a 2-pass LDS-bounce epilogue (eb[128][392], 16B-aligned rows).
__global__ __launch_bounds__(768, 3) void gemmQKV(const ushort* __restrict__ A,
        const ushort* __restrict__ Bt, ushort* __restrict__ q0, ushort* __restrict__ k0,
        ushort* __restrict__ v0, const float* __restrict__ cosT,
        const float* __restrict__ sinT) {
    extern __shared__ char smem[];
    // LDS map: A buf0 @0 (32K), A buf1 @32768, B buf0 @65536 (48K), B buf1 @114688.
    const int tid = threadIdx.x, lane = tid & 63, wv = tid >> 6;   // wv 0..11
    const int wm = wv / 6, wn = wv % 6;
    const int l15 = lane & 15, lg = lane >> 4;
    const int swzb = ((int)blockIdx.x & 7) * 32 + ((int)blockIdx.x >> 3);
    const int bn = (swzb & 15) * 384, bm = (swzb >> 4) * 256;

    f32x4 acc[8][4] = {};

    // staging addresses
    const int srow = lane >> 3;                      // 0..7 row within 8-row group
    const int swc = ((lane & 7) ^ srow) * 8;         // pre-swizzled 16B chunk (ushorts)
    const bool isA = (wv < 4), isB = (wv >= 4 && wv < 10);
    const ushort* Sg = isA ? (A + (size_t)(bm + wv * 64 + srow) * K_ + swc)
                           : (Bt + (size_t)(bn + (wv - 4) * 64 + srow) * K_ + swc);
    const int aoff = wv * 8192;            // A chunk offset (valid when isA)
    const int boff = (wv - 4) * 8192;      // B chunk offset (valid when isB)
    const size_t row8 = (size_t)8 * K_;

#define STGA(t) do { if (isA && (t) < 32) { \
        char* l0 = smem + (((t) & 1) ? 32768 : 0) + aoff; \
        const ushort* g0 = Sg + (size_t)(t) * 64; \
        _Pragma("unroll") for (int g = 0; g < 8; ++g) GLL16(g0 + g * row8, l0 + g * 1024); } } while (0)
#define STGB(t) do { if (isB && (t) < 32) { \
        char* l0 = smem + 65536 + (((t) & 1) ? 49152 : 0) + boff; \
        const ushort* g0 = Sg + (size_t)(t) * 64; \
        _Pragma("unroll") for (int g = 0; g < 8; ++g) GLL16(g0 + g * row8, l0 + g * 1024); } } while (0)

    const int colsw0 = (lg * 16) ^ ((l15 & 7) << 4);
    const int colsw1 = (64 + lg * 16) ^ ((l15 & 7) << 4);
    const char* ae = smem + wm * 16384;              // buf0-A, this wave's 2 chunks
    const char* ao = ae + 32768;
    const char* be = smem + 65536 + wn * 8192;       // buf0-B, this wave's chunk
    const char* bo = be + 49152;

#define LDA(ab, q, cs) do { _Pragma("unroll") for (int f = 0; f < 4; ++f) \
        a[f] = *reinterpret_cast<const short8*>((ab) + (q) * 8192 + (f * 16 + l15) * 128 + (cs)); } while (0)
#define LDB(bb, cs) do { _Pragma("unroll") for (int c = 0; c < 4; ++c) \
        b[c] = *reinterpret_cast<const short8*>((bb) + (c * 16 + l15) * 128 + (cs)); } while (0)
#define MM(q) do { __builtin_amdgcn_s_setprio(1); \
        _Pragma("unroll") for (int f = 0; f < 4; ++f) \
        _Pragma("unroll") for (int c = 0; c < 4; ++c) \
            acc[(q) * 4 + f][c] = __builtin_amdgcn_mfma_f32_16x16x32_bf16(a[f], b[c], acc[(q) * 4 + f][c], 0, 0, 0); \
        __builtin_amdgcn_s_setprio(0); } while (0)

    // prologue: tile0 (A+B) + tile1 B; A waits its 8, B keeps newest 8 in flight
    STGA(0); STGB(0);
    STGB(1);
    if (wv < 4) VMC0(); else if (wv < 10) VMC8();
    BAR8();

    for (int i = 0; i < 16; ++i) {
        const int t1 = 2 * i + 1, s0 = 2 * i + 2, s1 = 2 * i + 3;
        short8 a[4], b[4];
        // P1: tile e=2i (buf0), q0/k-lo; A-waves stage A(t1)->buf1 (freed prev P8)
        LDB(be, colsw0); LDA(ae, 0, colsw0);
        STGA(t1);
        BAR8(); MM(0); BAR8();
        // P2: q1/k-lo
        LDA(ae, 1, colsw0);
        BAR8(); MM(1); BAR8();
        // P3: q0/k-hi (last B-read of tile e)
        LDB(be, colsw1); LDA(ae, 0, colsw1);
        BAR8(); MM(0); BAR8();
        // P4: q1/k-hi; B-waves stage B(s0)->buf0-B (freed at P3 barrier);
        //     waits: A needs A(t1) resident; B needs B(o=t1) resident (keep s0)
        LDA(ae, 1, colsw1);
        STGB(s0);
        if (wv < 4) { VMC0(); } else if (wv < 10) { if (s0 < 32) VMC8(); else VMC0(); }
        BAR8(); MM(1); BAR8();
        // P5: tile o=2i+1 (buf1), q0/k-lo; A-waves stage A(s0)->buf0-A (freed P4)
        LDB(bo, colsw0); LDA(ao, 0, colsw0);
        STGA(s0);
        BAR8(); MM(0); BAR8();
        // P6: q1/k-lo
        LDA(ao, 1, colsw0);
        BAR8(); MM(1); BAR8();
        // P7: q0/k-hi (last B-read of tile o)
        LDB(bo, colsw1); LDA(ao, 0, colsw1);
        BAR8(); MM(0); BAR8();
        // P8: q1/k-hi; B-waves stage B(s1)->buf1-B (freed P7);
        //     waits: A needs A(s0) resident; B needs B(s0) resident (keep s1)
        LDA(ao, 1, colsw1);
        STGB(s1);
        if (wv < 4) { VMC0(); } else if (wv < 10) { if (s1 < 32) VMC8(); else VMC0(); }
        BAR8(); MM(1); BAR8();
    }

    // ---- 2-pass LDS-bounce epilogue with fused RoPE ----
    // eb[128][392] bf16 = 100.4 KB; row stride 784B = 49x16 (16B-aligned).
    ushort* eb = (ushort*)smem;
    #pragma unroll
    for (int p = 0; p < 2; ++p) {
        __syncthreads();
        if (wm == p) {
            #pragma unroll
            for (int c = 0; c < 4; ++c)
                #pragma unroll
                for (int rf = 0; rf < 8; ++rf)
                    #pragma unroll
                    for (int j = 0; j < 4; ++j) {
                        int r = rf * 16 + lg * 4 + j;               // 0..127
                        int cl = wn * 64 + c * 16 + l15;            // 0..383
                        eb[r * 392 + cl] = f2bf(acc[rf][c][j]);
                    }
        }
        __syncthreads();
        // store: 768 threads over 128 rows (6 threads/row), 48 16B-chunks/row
        const int row = tid / 6, t6 = tid - row * 6;
        const int grow = bm + p * 128 + row;
        const int bb = grow >> 11, s = grow & (S_ - 1);
        const float* cr = cosT + (size_t)s * 64;
        const float* sr = sinT + (size_t)s * 64;
        const ushort* ebr = eb + row * 392;
        #pragma unroll
        for (int cc = 0; cc < 8; ++cc) {
            const int coln = (t6 + cc * 6) * 8;     // 0..376 step 8
            const int colg = bn + coln;
            const int seg = colg >> 11;
            const int h = (colg >> 7) & (H_ - 1), d = colg & (HD_ - 1);
            short8 v8 = *reinterpret_cast<const short8*>(ebr + coln);
            if (seg != 1)   // reference rotates q and v, not k
                v8 = rope8(v8, cr + (d >> 1), sr + (d >> 1));
            ushort* segp = (seg == 0) ? q0 : ((seg == 1) ? k0 : v0);
            *reinterpret_cast<short8*>(segp + (((size_t)(bb * H_ + h)) * S_ + s) * HD_ + d) = v8;
        }
    }
#undef STGA
#undef STGB
#undef LDA
#undef LDB
#undef MM
}

// ============== out-proj GEMM: 256x128, 8 waves (4x2), per-wave 64x64 ==============
// 8-phase deep-lead structure (round-13 MODE 1, unchanged). N=2048 -> f32; 256 wgs.
__global__ __launch_bounds__(512, 2) void gemmOut(const ushort* __restrict__ A,
        const ushort* __restrict__ Bt, float* __restrict__ outf, int nbx) {
    constexpr int NC = 4, NF = 2, ACCR = 4, NBCH = 2, WCOLS = 64;
    constexpr int BBYTES = 128 * 128, BSTRIDE = 32768 + BBYTES;

    extern __shared__ char smem[];
    const int tid = threadIdx.x, lane = tid & 63, wv = tid >> 6;
    const int wm = wv >> 1, wn = wv & 1;
    const int l15 = lane & 15, lg = lane >> 4;
    const int nwg = (int)gridDim.x, cpx = nwg >> 3;
    const int swzb = ((int)blockIdx.x & 7) * cpx + ((int)blockIdx.x >> 3);
    const int bn = (swzb % nbx) * 128, bm = (swzb / nbx) * 256;

    f32x4 acc[ACCR][NC] = {};

    const int grl = wv * 8 + (lane >> 3);
    const int swc = (((lane & 7) ^ ((lane >> 3) & 7)) * 8);
    const ushort* Ag = A + (size_t)(bm + grl) * K_ + swc;
    const ushort* Bg = Bt + (size_t)(bn + grl) * K_ + swc;
    const size_t rowHA = (size_t)128 * K_;
    const size_t row64 = (size_t)64 * K_;

#define VMCN() asm volatile("s_waitcnt vmcnt(2)" ::: "memory")
#define STAGE_A(t, h) do { if ((t) < 32) { \
        const ushort* g = Ag + (size_t)(h) * rowHA + (size_t)(t) * 64; \
        char* l = smem + (((t) & 1) ? BSTRIDE : 0) + ((h) << 14) + (wv << 10); \
        GLL16(g, l); GLL16(g + row64, l + 8192); } } while (0)
#define STAGE_B(t, ch) do { if ((t) < 32) { \
        const ushort* g = Bg + (size_t)(ch) * row64 + (size_t)(t) * 64; \
        char* l = smem + (((t) & 1) ? BSTRIDE : 0) + 32768 + (ch) * 8192 + (wv << 10); \
        GLL16(g, l); } } while (0)
#define STAGE_B_ALL(t) do { _Pragma("unroll") \
        for (int ch = 0; ch < NBCH; ++ch) STAGE_B(t, ch); } while (0)

    const int colsw0 = (lg * 16) ^ ((l15 & 7) << 4);
    const int colsw1 = (64 + lg * 16) ^ ((l15 & 7) << 4);
    const char* abase0 = smem + wm * (NF * 4096);
    const char* bbase0 = smem + 32768;
    const char* abase1 = abase0 + BSTRIDE;
    const char* bbase1 = bbase0 + BSTRIDE;

#define LDA(ab, q, cs) do { _Pragma("unroll") for (int f = 0; f < NF; ++f) \
        a[f] = *reinterpret_cast<const short8*>((ab) + ((q) * (NF * 16) + f * 16 + l15) * 128 + (cs)); } while (0)
#define LDB(bb, cs) do { _Pragma("unroll") for (int c = 0; c < NC; ++c) { \
        const int rw = wn * WCOLS + c * 16; \
        b[c] = *reinterpret_cast<const short8*>((bb) + (rw >> 6) * 8192 + ((rw & 63) + l15) * 128 + (cs)); } } while (0)
#define MM(q) do { __builtin_amdgcn_s_setprio(1); \
        _Pragma("unroll") for (int f = 0; f < NF; ++f) \
        _Pragma("unroll") for (int c = 0; c < NC; ++c) \
            acc[(q) * NF + f][c] = __builtin_amdgcn_mfma_f32_16x16x32_bf16(a[f], b[c], acc[(q) * NF + f][c], 0, 0, 0); \
        __builtin_amdgcn_s_setprio(0); } while (0)

    STAGE_A(0, 0); STAGE_A(0, 1);
    STAGE_B_ALL(0);
    STAGE_B_ALL(1);
    VMCN();
    BAR8();

    for (int i = 0; i < 16; ++i) {
        const int t1 = 2 * i + 1, s0 = 2 * i + 2, s1 = 2 * i + 3;
        short8 a[NF], b[NC];
        LDB(bbase0, colsw0); LDA(abase0, 0, colsw0);
        STAGE_A(t1, 0);
        BAR8(); MM(0); BAR8();
        LDA(abase0, 1, colsw0);
        STAGE_A(t1, 1);
        BAR8(); MM(1); BAR8();
        LDB(bbase0, colsw1); LDA(abase0, 0, colsw1);
        BAR8(); MM(0); BAR8();
        LDA(abase0, 1, colsw1);
        STAGE_B_ALL(s0);
        if (s0 < 32) VMCN(); else VMC0();
        BAR8(); MM(1); BAR8();
        LDB(bbase1, colsw0); LDA(abase1, 0, colsw0);
        STAGE_A(s0, 0);
        BAR8(); MM(0); BAR8();
        LDA(abase1, 1, colsw0);
        STAGE_A(s0, 1);
        BAR8(); MM(1); BAR8();
        LDB(bbase1, colsw1); LDA(abase1, 0, colsw1);
        BAR8(); MM(0); BAR8();
        LDA(abase1, 1, colsw1);
        STAGE_B_ALL(s1);
        if (s1 < 32) VMCN(); else VMC0();
        BAR8(); MM(1); BAR8();
    }

    #pragma unroll
    for (int rf = 0; rf < ACCR; ++rf)
        #pragma unroll
        for (int c = 0; c < NC; ++c)
            #pragma unroll
            for (int j = 0; j < 4; ++j) {
                int row = bm + wm * (NF * 32) + rf * 16 + lg * 4 + j;
                int col = bn + wn * WCOLS + c * 16 + l15;
                outf[(size_t)row * D_ + col] = acc[rf][c][j];
            }
#undef VMCN
#undef STAGE_A
#undef STAGE_B
#undef STAGE_B_ALL
#undef LDA
#undef LDB
#undef MM
}

// ============ causal flash attention v5: 8 waves, 128 q-rows/block ============
__global__ __launch_bounds__(512, 4) void attn5(const ushort* __restrict__ Qm,
        const ushort* __restrict__ Km, const ushort* __restrict__ Vm,
        ushort* __restrict__ Om) {
    __shared__ __align__(16) ushort Kb[2][64 * 128];   // swizzled [key][d], 16KB each
    __shared__ __align__(16) ushort Vt[2][128][72];    // [d][key]
    const int tid = threadIdx.x, lane = tid & 63, wv = tid >> 6;
    const int l15 = lane & 15, lg = lane >> 4;
    const int yy = (int)blockIdx.y;
    const int qt = (yy < 8) ? (15 - 2 * yy) : (2 * (yy - 8));
    const int bh = blockIdx.x;
    const size_t base = (size_t)bh * S_ * HD_;
    const int qrow0 = qt * 128 + wv * 16;
    const float C = 0.1275174f;            // (1/sqrt(128)) * log2(e)

    short8 qf[4];
    {
        const ushort* qp = Qm + base + (size_t)(qrow0 + l15) * HD_;
        #pragma unroll
        for (int c = 0; c < 4; ++c)
            qf[c] = *reinterpret_cast<const short8*>(qp + c * 32 + lg * 8);
    }
    f32x4 oacc[8] = {};
    float mS = -1e30f, lS = 0.f;
    const int ntiles = 2 * qt + 2;
    const int kmask0 = 2 * qt + (wv >> 2);

    {
        #pragma unroll
        for (int c = 0; c < 2; ++c) {
            int row = wv * 8 + c * 4 + (lane >> 4);
            GLL16(Km + base + (size_t)row * HD_ + (((lane & 15) ^ (row & 7)) << 3),
                  &Kb[0][wv * 1024 + c * 512]);
        }
        const ushort* vp = Vm + base + (size_t)lane * HD_ + wv * 16;
        #pragma unroll
        for (int cc = 0; cc < 2; ++cc) {
            int4v v = *reinterpret_cast<const int4v*>(vp + cc * 8);
            const ushort* e = reinterpret_cast<const ushort*>(&v);
            #pragma unroll
            for (int j = 0; j < 8; ++j) Vt[0][wv * 16 + cc * 8 + j][lane] = e[j];
        }
    }
    __syncthreads();

    int cur = 0;
    for (int kt = 0; kt < ntiles; ++kt) {
        const bool pfn = (kt + 1 < ntiles);
        int4v vr[2];
        if (pfn) {
            const int r0 = (kt + 1) * 64;
            #pragma unroll
            for (int c = 0; c < 2; ++c) {
                int row = wv * 8 + c * 4 + (lane >> 4);
                GLL16(Km + base + (size_t)(r0 + row) * HD_ + (((lane & 15) ^ (row & 7)) << 3),
                      &Kb[cur ^ 1][wv * 1024 + c * 512]);
            }
            const ushort* vp = Vm + base + (size_t)(r0 + lane) * HD_ + wv * 16;
            #pragma unroll
            for (int cc = 0; cc < 2; ++cc)
                vr[cc] = *reinterpret_cast<const int4v*>(vp + cc * 8);
        }
        f32x4 sacc[4] = {};
        const ushort* Kc = &Kb[cur][0];
        __builtin_amdgcn_s_setprio(1);
        #pragma unroll
        for (int ct = 0; ct < 4; ++ct) {
            const int row = ct * 16 + l15;
            const int sw = (row & 7) << 3;
            #pragma unroll
            for (int c = 0; c < 4; ++c) {
                short8 kf = *reinterpret_cast<const short8*>(
                    Kc + row * 128 + ((c * 32 + lg * 8) ^ sw));
                sacc[ct] = __builtin_amdgcn_mfma_f32_16x16x32_bf16(kf, qf[c], sacc[ct], 0, 0, 0);
            }
        }
        __builtin_amdgcn_s_setprio(0);

        float t16[16];
        #pragma unroll
        for (int ct = 0; ct < 4; ++ct)
            #pragma unroll
            for (int j = 0; j < 4; ++j) t16[ct * 4 + j] = sacc[ct][j];
        if (kt >= kmask0) {
            const int thr = qrow0 + l15 - kt * 64;
            #pragma unroll
            for (int ct = 0; ct < 4; ++ct)
                #pragma unroll
                for (int j = 0; j < 4; ++j)
                    if (ct * 16 + lg * 4 + j > thr) t16[ct * 4 + j] = -1e30f;
        }
        float mx[8];
        #pragma unroll
        for (int i = 0; i < 8; ++i) mx[i] = fmaxf(t16[i], t16[i + 8]);
        #pragma unroll
        for (int i = 0; i < 4; ++i) mx[i] = fmaxf(mx[i], mx[i + 4]);
        float m64 = fmaxf(fmaxf(mx[0], mx[1]), fmaxf(mx[2], mx[3]));
        m64 = fmaxf(m64, __shfl_xor(m64, 16));
        m64 = fmaxf(m64, __shfl_xor(m64, 32));
        if (!__all(m64 - mS <= 47.0f)) {
            float mnew = fmaxf(mS, m64);
            float corr = __builtin_amdgcn_exp2f((mS - mnew) * C);
            lS *= corr;
            #pragma unroll
            for (int dt = 0; dt < 8; ++dt)
                #pragma unroll
                for (int j = 0; j < 4; ++j) oacc[dt][j] *= corr;
            mS = mnew;
        }
        const float mcc = mS * C;
        float p[16];
        #pragma unroll
        for (int i = 0; i < 16; ++i)
            p[i] = __builtin_amdgcn_exp2f(fmaf(t16[i], C, -mcc));
        float sm[8];
        #pragma unroll
        for (int i = 0; i < 8; ++i) sm[i] = p[i] + p[i + 8];
        #pragma unroll
        for (int i = 0; i < 4; ++i) sm[i] = sm[i] + sm[i + 4];
        float psum = (sm[0] + sm[1]) + (sm[2] + sm[3]);
        psum += __shfl_xor(psum, 16);
        psum += __shfl_xor(psum, 32);
        lS += psum;

        unsigned dw[8];
        #pragma unroll
        for (int ct = 0; ct < 4; ++ct)
            #pragma unroll
            for (int u = 0; u < 2; ++u) {
                __hip_bfloat162 h2 = __float22bfloat162_rn(
                    float2{p[ct * 4 + 2 * u], p[ct * 4 + 2 * u + 1]});
                dw[ct * 2 + u] = *reinterpret_cast<unsigned*>(&h2);
            }
        #pragma unroll
        for (int c2 = 0; c2 < 2; ++c2) {
            int4v pfd;
            #pragma unroll
            for (int d = 0; d < 4; ++d) {
                int srcl = (lg & 1) * 32 + (d >> 1) * 16 + l15;
                int r0 = __shfl((int)dw[(2 * c2) * 2 + (d & 1)], srcl);
                int r1 = __shfl((int)dw[(2 * c2 + 1) * 2 + (d & 1)], srcl);
                pfd[d] = (lg & 2) ? r1 : r0;
            }
            short8 pf = *reinterpret_cast<short8*>(&pfd);
            __builtin_amdgcn_s_setprio(1);
            #pragma unroll
            for (int dt = 0; dt < 8; ++dt) {
                short8 vf = *reinterpret_cast<const short8*>(
                    &Vt[cur][dt * 16 + l15][c2 * 32 + lg * 8]);
                oacc[dt] = __builtin_amdgcn_mfma_f32_16x16x32_bf16(vf, pf, oacc[dt], 0, 0, 0);
            }
            __builtin_amdgcn_s_setprio(0);
        }
        if (pfn) {
            #pragma unroll
            for (int cc = 0; cc < 2; ++cc) {
                const ushort* e = reinterpret_cast<const ushort*>(&vr[cc]);
                #pragma unroll
                for (int j = 0; j < 8; ++j) Vt[cur ^ 1][wv * 16 + cc * 8 + j][lane] = e[j];
            }
        }
        __syncthreads();
        cur ^= 1;
    }
    const int b = bh >> 4, h = bh & (H_ - 1);
    const int q = qrow0 + l15;
    const float inv = 1.0f / lS;
    ushort* op = Om + ((size_t)(b * S_ + q)) * D_ + h * HD_;
    #pragma unroll
    for (int dt = 0; dt < 8; ++dt) {
        ushort4 o;
        o.x = f2bf(oacc[dt][0] * inv);
        o.y = f2bf(oacc[dt][1] * inv);
        o.z = f2bf(oacc[dt][2] * inv);
        o.w = f2bf(oacc[dt][3] * inv);
        *reinterpret_cast<ushort4*>(op + dt * 16 + lg * 4) = o;
    }
}

extern "C" void kernel_launch(void* const* d_in, const int* in_sizes, int n_in,
                              void* d_out, int out_size, void* d_ws, size_t ws_size,
                              hipStream_t stream) {
    const float* x    = (const float*)d_in[0];
    const float* cosT = (const float*)d_in[1];
    const float* sinT = (const float*)d_in[2];
    const float* wq   = (const float*)d_in[3];
    const float* wk   = (const float*)d_in[4];
    const float* wv   = (const float*)d_in[5];
    const float* wo   = (const float*)d_in[6];
    float* out = (float*)d_out;

    char* ws = (char*)d_ws;
    const size_t szX = (size_t)B_ * S_ * D_ * 2;  // 16.78 MB
    const size_t szW = (size_t)D_ * D_ * 2;       // 8.39 MB
    ushort* xb   = (ushort*)(ws);
    ushort* wcat = (ushort*)(ws + szX);                 // [6144][2048] = wqT|wkT|wvT
    ushort* woT  = (ushort*)(ws + szX + 3 * szW);
    ushort* q0   = (ushort*)(ws + szX + 4 * szW);
    ushort* k0   = (ushort*)(ws + szX + 4 * szW + szX);
    ushort* v0   = (ushort*)(ws + szX + 4 * szW + 2 * szX);
    ushort* att  = xb;  // xb dead after QKV GEMM; reuse as attention output

    hipFuncSetAttribute(reinterpret_cast<const void*>(&gemmQKV),
                        hipFuncAttributeMaxDynamicSharedMemorySize, 163840);
    hipFuncSetAttribute(reinterpret_cast<const void*>(&gemmOut),
                        hipFuncAttributeMaxDynamicSharedMemorySize, 98304);

    // weights transpose (z 0-3) + x cast (z 4-5), one dispatch
    prep_kernel<<<dim3(D_ / 64, D_ / 64, 6), 256, 0, stream>>>(
        wq, wk, wv, wo, wcat, wcat + (size_t)D_ * D_, wcat + 2 * (size_t)D_ * D_, woT,
        x, xb);

    // fused QKV (+RoPE epilogue): M=4096, N=6144, 256x384 tiles -> 256 wgs = 1 round
    gemmQKV<<<256, 768, 163840, stream>>>(xb, wcat, q0, k0, v0, cosT, sinT);

    attn5<<<dim3(B_ * H_, S_ / 128), 512, 0, stream>>>(q0, k0, v0, att);

    // out projection: M=4096, N=2048, 256x128 tiles, per-wave 64x64 -> 256 wgs
    gemmOut<<<256, 512, 98304, stream>>>(att, woT, out, 16);
}

// Round 15
// 243.459 us; speedup vs baseline: 2.7841x; 2.7841x over previous
//
#include <hip/hip_runtime.h>
#include <hip/hip_bf16.h>

typedef short short8 __attribute__((ext_vector_type(8)));
typedef float f32x4 __attribute__((ext_vector_type(4)));
typedef int int4v __attribute__((ext_vector_type(4)));

#define B_ 2
#define S_ 2048
#define D_ 2048
#define H_ 16
#define HD_ 128
#define K_ 2048   // GEMM K (both projections)

#define GLL16(gp, lp) __builtin_amdgcn_global_load_lds( \
    (const __attribute__((address_space(1))) void*)(gp), \
    (__attribute__((address_space(3))) void*)(lp), 16, 0, 0)

__device__ inline ushort f2bf(float f) {
    union { float f; unsigned u; } v; v.f = f;
    unsigned r = v.u + 0x7FFFu + ((v.u >> 16) & 1u);
    return (ushort)(r >> 16);
}
__device__ inline float bf2f(ushort b) {
    union { unsigned u; float f; } v; v.u = ((unsigned)b) << 16;
    return v.f;
}

// rope 4 (even,odd) bf16 pairs in-register; cosp/sinp point at 4 consecutive f32
__device__ inline short8 rope8(short8 raw, const float* __restrict__ cosp,
                               const float* __restrict__ sinp) {
    float4 cs = *reinterpret_cast<const float4*>(cosp);
    float4 sn = *reinterpret_cast<const float4*>(sinp);
    const float* c = reinterpret_cast<const float*>(&cs);
    const float* s = reinterpret_cast<const float*>(&sn);
    short8 out;
    #pragma unroll
    for (int j = 0; j < 4; ++j) {
        float a = bf2f((ushort)raw[2 * j]), b = bf2f((ushort)raw[2 * j + 1]);
        out[2 * j]     = (short)f2bf(fmaf(a, c[j], -(b * s[j])));
        out[2 * j + 1] = (short)f2bf(fmaf(a, s[j], b * c[j]));
    }
    return out;
}

// z=0..3: w[K][N] f32 -> wT[N][K] bf16 via 64x64 LDS tile.
// z=4..5: fp32->bf16 cast of x (4 float4 chunks per block, stride 524288).
__global__ __launch_bounds__(256) void prep_kernel(
        const float* __restrict__ s0, const float* __restrict__ s1,
        const float* __restrict__ s2, const float* __restrict__ s3,
        ushort* __restrict__ d0, ushort* __restrict__ d1,
        ushort* __restrict__ d2, ushort* __restrict__ d3,
        const float* __restrict__ x, ushort* __restrict__ xb) {
    const int z = blockIdx.z;
    const int t = threadIdx.x;
    if (z >= 4) {
        const int lane = (((z - 4) * 1024 + blockIdx.y * 32 + blockIdx.x) << 8) + t;
        #pragma unroll
        for (int k = 0; k < 4; ++k) {
            int i = lane + k * 524288;
            float4 v = reinterpret_cast<const float4*>(x)[i];
            ushort4 o;
            o.x = f2bf(v.x); o.y = f2bf(v.y); o.z = f2bf(v.z); o.w = f2bf(v.w);
            reinterpret_cast<ushort4*>(xb)[i] = o;
        }
        return;
    }
    __shared__ ushort tile[64][72];
    const float* src = (z == 0) ? s0 : (z == 1) ? s1 : (z == 2) ? s2 : s3;
    ushort* dst = (z == 0) ? d0 : (z == 1) ? d1 : (z == 2) ? d2 : d3;
    const int bk = blockIdx.y * 64, bn = blockIdx.x * 64;
    #pragma unroll
    for (int it = 0; it < 4; ++it) {
        int id = t + it * 256;
        int row = id >> 4;
        int c4 = (id & 15) * 4;
        float4 v = *reinterpret_cast<const float4*>(&src[(size_t)(bk + row) * D_ + bn + c4]);
        ushort4 o; o.x = f2bf(v.x); o.y = f2bf(v.y); o.z = f2bf(v.z); o.w = f2bf(v.w);
        *reinterpret_cast<ushort4*>(&tile[row][c4]) = o;
    }
    __syncthreads();
    #pragma unroll
    for (int it = 0; it < 4; ++it) {
        int id = t + it * 256;
        int n = id >> 4;
        int c4 = (id & 15) * 4;
        ushort4 o;
        o.x = tile[c4 + 0][n]; o.y = tile[c4 + 1][n];
        o.z = tile[c4 + 2][n]; o.w = tile[c4 + 3][n];
        *reinterpret_cast<ushort4*>(&dst[(size_t)(bn + n) * D_ + bk + c4]) = o;
    }
}

// ===================== 256xBN 8-phase GEMM (T1+T2+T3+T4+T5) =====================
// MODE 0: BN=192, waves 2x4 (per-wave 128x48), N=6144 fused QKV -> bf16 (B,H,S,HD)
//         with RoPE fused in a coalesced LDS-bounce epilogue; grid 512 = 2 rounds.
// MODE 1: BN=128, waves 4x2 (per-wave 64x64), N=2048 -> f32; grid 256 = 1 round.
// Deep-lead stage order; counted vmcnt (oldest-7 rule) -> vmcnt(NBCH), tails drain 0.
// NOTE (r14 lesson): 2 blocks/CU + this tile size is what preserves per-XCD L2
// locality (FETCH ~205MB); bigger 1-block/CU tiles thrash L2 (FETCH 760MB).
#define BAR8() __builtin_amdgcn_s_barrier()
#define VMC0() asm volatile("s_waitcnt vmcnt(0)" ::: "memory")

template<int MODE>
__global__ __launch_bounds__(512, 2) void gemm8(const ushort* __restrict__ A,
        const ushort* __restrict__ Bt, ushort* __restrict__ q0, ushort* __restrict__ k0,
        ushort* __restrict__ v0, float* __restrict__ outf,
        const float* __restrict__ cosT, const float* __restrict__ sinT, int nbx) {
    constexpr int NC      = (MODE == 0) ? 3 : 4;       // col frags per wave
    constexpr int NF      = (MODE == 0) ? 4 : 2;       // row frags per MM
    constexpr int ACCR    = NF * 2;                    // acc rows: 8 / 4
    constexpr int BN      = (MODE == 0) ? 192 : 128;
    constexpr int NBCH    = BN / 64;                   // B chunks per tile: 3 / 2
    constexpr int WCOLS   = (MODE == 0) ? 48 : 64;     // cols per wave
    constexpr int BBYTES  = BN * 128;                  // B bytes per buf
    constexpr int BSTRIDE = 32768 + BBYTES;            // 57344 / 49152

    extern __shared__ char smem[];
    const int tid = threadIdx.x, lane = tid & 63, wv = tid >> 6;
    const int wm = (MODE == 0) ? (wv >> 2) : (wv >> 1);
    const int wn = (MODE == 0) ? (wv & 3) : (wv & 1);
    const int l15 = lane & 15, lg = lane >> 4;
    const int nwg = (int)gridDim.x, cpx = nwg >> 3;
    const int swzb = ((int)blockIdx.x & 7) * cpx + ((int)blockIdx.x >> 3);
    const int bn = (swzb % nbx) * BN, bm = (swzb / nbx) * 256;

    f32x4 acc[ACCR][NC] = {};

    const int grl = wv * 8 + (lane >> 3);
    const int swc = (((lane & 7) ^ ((lane >> 3) & 7)) * 8);
    const ushort* Ag = A + (size_t)(bm + grl) * K_ + swc;
    const ushort* Bg = Bt + (size_t)(bn + grl) * K_ + swc;
    const size_t rowHA = (size_t)128 * K_;   // A half stride (rows)
    const size_t row64 = (size_t)64 * K_;    // 64-row chunk stride

#define VMCN() do { if (MODE == 0) asm volatile("s_waitcnt vmcnt(3)" ::: "memory"); \
                    else           asm volatile("s_waitcnt vmcnt(2)" ::: "memory"); } while (0)
#define STAGE_A(t, h) do { if ((t) < 32) { \
        const ushort* g = Ag + (size_t)(h) * rowHA + (size_t)(t) * 64; \
        char* l = smem + (((t) & 1) ? BSTRIDE : 0) + ((h) << 14) + (wv << 10); \
        GLL16(g, l); GLL16(g + row64, l + 8192); } } while (0)
#define STAGE_B(t, ch) do { if ((t) < 32) { \
        const ushort* g = Bg + (size_t)(ch) * row64 + (size_t)(t) * 64; \
        char* l = smem + (((t) & 1) ? BSTRIDE : 0) + 32768 + (ch) * 8192 + (wv << 10); \
        GLL16(g, l); } } while (0)
#define STAGE_B_ALL(t) do { _Pragma("unroll") \
        for (int ch = 0; ch < NBCH; ++ch) STAGE_B(t, ch); } while (0)

    const int colsw0 = (lg * 16) ^ ((l15 & 7) << 4);
    const int colsw1 = (64 + lg * 16) ^ ((l15 & 7) << 4);
    const char* abase0 = smem + wm * (NF * 4096);
    const char* bbase0 = smem + 32768;
    const char* abase1 = abase0 + BSTRIDE;
    const char* bbase1 = bbase0 + BSTRIDE;

#define LDA(ab, q, cs) do { _Pragma("unroll") for (int f = 0; f < NF; ++f) \
        a[f] = *reinterpret_cast<const short8*>((ab) + ((q) * (NF * 16) + f * 16 + l15) * 128 + (cs)); } while (0)
#define LDB(bb, cs) do { _Pragma("unroll") for (int c = 0; c < NC; ++c) { \
        const int rw = wn * WCOLS + c * 16; \
        b[c] = *reinterpret_cast<const short8*>((bb) + (rw >> 6) * 8192 + ((rw & 63) + l15) * 128 + (cs)); } } while (0)
#define MM(q) do { __builtin_amdgcn_s_setprio(1); \
        _Pragma("unroll") for (int f = 0; f < NF; ++f) \
        _Pragma("unroll") for (int c = 0; c < NC; ++c) \
            acc[(q) * NF + f][c] = __builtin_amdgcn_mfma_f32_16x16x32_bf16(a[f], b[c], acc[(q) * NF + f][c], 0, 0, 0); \
        __builtin_amdgcn_s_setprio(0); } while (0)

    // prologue: tile0 (A 4 + B NBCH) + tile1 B (NBCH) -> wait oldest 7
    STAGE_A(0, 0); STAGE_A(0, 1);
    STAGE_B_ALL(0);
    STAGE_B_ALL(1);
    VMCN();
    BAR8();

    for (int i = 0; i < 16; ++i) {
        const int t1 = 2 * i + 1, s0 = 2 * i + 2, s1 = 2 * i + 3;
        short8 a[NF], b[NC];
        // ph1: tile 2i (buf0); A(t1) into buf1-A (freed at prev ph8)
        LDB(bbase0, colsw0); LDA(abase0, 0, colsw0);
        STAGE_A(t1, 0);
        BAR8(); MM(0); BAR8();
        // ph2
        LDA(abase0, 1, colsw0);
        STAGE_A(t1, 1);
        BAR8(); MM(1); BAR8();
        // ph3: last B-read of tile 2i
        LDB(bbase0, colsw1); LDA(abase0, 0, colsw1);
        BAR8(); MM(0); BAR8();
        // ph4: B(s0) into buf0-B (freed at ph3); wait tile t1 resident (oldest 7)
        LDA(abase0, 1, colsw1);
        STAGE_B_ALL(s0);
        if (s0 < 32) VMCN(); else VMC0();
        BAR8(); MM(1); BAR8();
        // ph5: tile 2i+1 (buf1); A(s0) into buf0-A (freed at ph4)
        LDB(bbase1, colsw0); LDA(abase1, 0, colsw0);
        STAGE_A(s0, 0);
        BAR8(); MM(0); BAR8();
        // ph6
        LDA(abase1, 1, colsw0);
        STAGE_A(s0, 1);
        BAR8(); MM(1); BAR8();
        // ph7: last B-read of tile 2i+1
        LDB(bbase1, colsw1); LDA(abase1, 0, colsw1);
        BAR8(); MM(0); BAR8();
        // ph8: B(s1) into buf1-B (freed at ph7); wait tile s0 resident
        LDA(abase1, 1, colsw1);
        STAGE_B_ALL(s1);
        if (s1 < 32) VMCN(); else VMC0();
        BAR8(); MM(1); BAR8();
    }

    if (MODE == 0) {
        // ---- LDS-bounce epilogue with fused RoPE (conflict/coalesce-fixed) ----
        // eb[256][216] bf16 = 108 KB <= 112 KB. Row stride 432B = 27x16 (16B-aligned);
        // 432*lg = 16*lg mod 32 banks -> write pattern is a free 2-way.
        ushort* eb = (ushort*)smem;
        #pragma unroll
        for (int c = 0; c < NC; ++c)
            #pragma unroll
            for (int rf = 0; rf < ACCR; ++rf)
                #pragma unroll
                for (int j = 0; j < 4; ++j) {
                    int r = wm * 128 + rf * 16 + lg * 4 + j;
                    int cl = wn * WCOLS + c * 16 + l15;
                    eb[r * 216 + cl] = f2bf(acc[rf][c][j]);
                }
        __syncthreads();
        // store phase: 4 lanes per row, chunk-major. Each 4-lane group writes 64B
        // contiguous in one (h,s) row; groups never straddle head boundaries
        // (bn % 32 == 0, head boundary every 128 cols, group span 32 cols).
        const int rql = lane >> 2;       // 0..15 row within wave-pass
        const int cgrp = lane & 3;       // 16B chunk group
        #pragma unroll
        for (int p = 0; p < 2; ++p) {
            const int row = p * 128 + wv * 16 + rql;
            const int grow = bm + row;
            const int bb = grow >> 11, s = grow & (S_ - 1);
            const float* cr = cosT + (size_t)s * 64;
            const float* sr = sinT + (size_t)s * 64;
            const ushort* ebr = eb + row * 216;
            #pragma unroll
            for (int t = 0; t < 6; ++t) {
                const int coln = (cgrp + t * 4) * 8;     // 0..184, step 8 cols
                const int colg = bn + coln;
                const int seg = colg >> 11;
                const int h = (colg >> 7) & (H_ - 1), d = colg & (HD_ - 1);
                short8 v8 = *reinterpret_cast<const short8*>(ebr + coln);
                if (seg != 1)   // reference rotates q and v, not k
                    v8 = rope8(v8, cr + (d >> 1), sr + (d >> 1));
                ushort* segp = (seg == 0) ? q0 : ((seg == 1) ? k0 : v0);
                *reinterpret_cast<short8*>(segp + (((size_t)(bb * H_ + h)) * S_ + s) * HD_ + d) = v8;
            }
        }
    } else {
        #pragma unroll
        for (int rf = 0; rf < ACCR; ++rf)
            #pragma unroll
            for (int c = 0; c < NC; ++c)
                #pragma unroll
                for (int j = 0; j < 4; ++j) {
                    int row = bm + wm * (NF * 32) + rf * 16 + lg * 4 + j;
                    int col = bn + wn * WCOLS + c * 16 + l15;
                    outf[(size_t)row * D_ + col] = acc[rf][c][j];
                }
    }
#undef VMCN
#undef STAGE_A
#undef STAGE_B
#undef STAGE_B_ALL
#undef LDA
#undef LDB
#undef MM
}

// ============ causal flash attention v5: 8 waves, 128 q-rows/block ============
__global__ __launch_bounds__(512, 4) void attn5(const ushort* __restrict__ Qm,
        const ushort* __restrict__ Km, const ushort* __restrict__ Vm,
        ushort* __restrict__ Om) {
    __shared__ __align__(16) ushort Kb[2][64 * 128];   // swizzled [key][d], 16KB each
    __shared__ __align__(16) ushort Vt[2][128][72];    // [d][key]
    const int tid = threadIdx.x, lane = tid & 63, wv = tid >> 6;
    const int l15 = lane & 15, lg = lane >> 4;
    const int yy = (int)blockIdx.y;
    const int qt = (yy < 8) ? (15 - 2 * yy) : (2 * (yy - 8));
    const int bh = blockIdx.x;
    const size_t base = (size_t)bh * S_ * HD_;
    const int qrow0 = qt * 128 + wv * 16;
    const float C = 0.1275174f;            // (1/sqrt(128)) * log2(e)

    short8 qf[4];
    {
        const ushort* qp = Qm + base + (size_t)(qrow0 + l15) * HD_;
        #pragma unroll
        for (int c = 0; c < 4; ++c)
            qf[c] = *reinterpret_cast<const short8*>(qp + c * 32 + lg * 8);
    }
    f32x4 oacc[8] = {};
    float mS = -1e30f, lS = 0.f;
    const int ntiles = 2 * qt + 2;
    const int kmask0 = 2 * qt + (wv >> 2);

    {
        #pragma unroll
        for (int c = 0; c < 2; ++c) {
            int row = wv * 8 + c * 4 + (lane >> 4);
            GLL16(Km + base + (size_t)row * HD_ + (((lane & 15) ^ (row & 7)) << 3),
                  &Kb[0][wv * 1024 + c * 512]);
        }
        const ushort* vp = Vm + base + (size_t)lane * HD_ + wv * 16;
        #pragma unroll
        for (int cc = 0; cc < 2; ++cc) {
            int4v v = *reinterpret_cast<const int4v*>(vp + cc * 8);
            const ushort* e = reinterpret_cast<const ushort*>(&v);
            #pragma unroll
            for (int j = 0; j < 8; ++j) Vt[0][wv * 16 + cc * 8 + j][lane] = e[j];
        }
    }
    __syncthreads();

    int cur = 0;
    for (int kt = 0; kt < ntiles; ++kt) {
        const bool pfn = (kt + 1 < ntiles);
        int4v vr[2];
        if (pfn) {
            const int r0 = (kt + 1) * 64;
            #pragma unroll
            for (int c = 0; c < 2; ++c) {
                int row = wv * 8 + c * 4 + (lane >> 4);
                GLL16(Km + base + (size_t)(r0 + row) * HD_ + (((lane & 15) ^ (row & 7)) << 3),
                      &Kb[cur ^ 1][wv * 1024 + c * 512]);
            }
            const ushort* vp = Vm + base + (size_t)(r0 + lane) * HD_ + wv * 16;
            #pragma unroll
            for (int cc = 0; cc < 2; ++cc)
                vr[cc] = *reinterpret_cast<const int4v*>(vp + cc * 8);
        }
        f32x4 sacc[4] = {};
        const ushort* Kc = &Kb[cur][0];
        __builtin_amdgcn_s_setprio(1);
        #pragma unroll
        for (int ct = 0; ct < 4; ++ct) {
            const int row = ct * 16 + l15;
            const int sw = (row & 7) << 3;
            #pragma unroll
            for (int c = 0; c < 4; ++c) {
                short8 kf = *reinterpret_cast<const short8*>(
                    Kc + row * 128 + ((c * 32 + lg * 8) ^ sw));
                sacc[ct] = __builtin_amdgcn_mfma_f32_16x16x32_bf16(kf, qf[c], sacc[ct], 0, 0, 0);
            }
        }
        __builtin_amdgcn_s_setprio(0);

        float t16[16];
        #pragma unroll
        for (int ct = 0; ct < 4; ++ct)
            #pragma unroll
            for (int j = 0; j < 4; ++j) t16[ct * 4 + j] = sacc[ct][j];
        if (kt >= kmask0) {
            const int thr = qrow0 + l15 - kt * 64;
            #pragma unroll
            for (int ct = 0; ct < 4; ++ct)
                #pragma unroll
                for (int j = 0; j < 4; ++j)
                    if (ct * 16 + lg * 4 + j > thr) t16[ct * 4 + j] = -1e30f;
        }
        float mx[8];
        #pragma unroll
        for (int i = 0; i < 8; ++i) mx[i] = fmaxf(t16[i], t16[i + 8]);
        #pragma unroll
        for (int i = 0; i < 4; ++i) mx[i] = fmaxf(mx[i], mx[i + 4]);
        float m64 = fmaxf(fmaxf(mx[0], mx[1]), fmaxf(mx[2], mx[3]));
        m64 = fmaxf(m64, __shfl_xor(m64, 16));
        m64 = fmaxf(m64, __shfl_xor(m64, 32));
        if (!__all(m64 - mS <= 47.0f)) {
            float mnew = fmaxf(mS, m64);
            float corr = __builtin_amdgcn_exp2f((mS - mnew) * C);
            lS *= corr;
            #pragma unroll
            for (int dt = 0; dt < 8; ++dt)
                #pragma unroll
                for (int j = 0; j < 4; ++j) oacc[dt][j] *= corr;
            mS = mnew;
        }
        const float mcc = mS * C;
        float p[16];
        #pragma unroll
        for (int i = 0; i < 16; ++i)
            p[i] = __builtin_amdgcn_exp2f(fmaf(t16[i], C, -mcc));
        float sm[8];
        #pragma unroll
        for (int i = 0; i < 8; ++i) sm[i] = p[i] + p[i + 8];
        #pragma unroll
        for (int i = 0; i < 4; ++i) sm[i] = sm[i] + sm[i + 4];
        float psum = (sm[0] + sm[1]) + (sm[2] + sm[3]);
        psum += __shfl_xor(psum, 16);
        psum += __shfl_xor(psum, 32);
        lS += psum;

        unsigned dw[8];
        #pragma unroll
        for (int ct = 0; ct < 4; ++ct)
            #pragma unroll
            for (int u = 0; u < 2; ++u) {
                __hip_bfloat162 h2 = __float22bfloat162_rn(
                    float2{p[ct * 4 + 2 * u], p[ct * 4 + 2 * u + 1]});
                dw[ct * 2 + u] = *reinterpret_cast<unsigned*>(&h2);
            }
        #pragma unroll
        for (int c2 = 0; c2 < 2; ++c2) {
            int4v pfd;
            #pragma unroll
            for (int d = 0; d < 4; ++d) {
                int srcl = (lg & 1) * 32 + (d >> 1) * 16 + l15;
                int r0 = __shfl((int)dw[(2 * c2) * 2 + (d & 1)], srcl);
                int r1 = __shfl((int)dw[(2 * c2 + 1) * 2 + (d & 1)], srcl);
                pfd[d] = (lg & 2) ? r1 : r0;
            }
            short8 pf = *reinterpret_cast<short8*>(&pfd);
            __builtin_amdgcn_s_setprio(1);
            #pragma unroll
            for (int dt = 0; dt < 8; ++dt) {
                short8 vf = *reinterpret_cast<const short8*>(
                    &Vt[cur][dt * 16 + l15][c2 * 32 + lg * 8]);
                oacc[dt] = __builtin_amdgcn_mfma_f32_16x16x32_bf16(vf, pf, oacc[dt], 0, 0, 0);
            }
            __builtin_amdgcn_s_setprio(0);
        }
        if (pfn) {
            #pragma unroll
            for (int cc = 0; cc < 2; ++cc) {
                const ushort* e = reinterpret_cast<const ushort*>(&vr[cc]);
                #pragma unroll
                for (int j = 0; j < 8; ++j) Vt[cur ^ 1][wv * 16 + cc * 8 + j][lane] = e[j];
            }
        }
        __syncthreads();
        cur ^= 1;
    }
    const int b = bh >> 4, h = bh & (H_ - 1);
    const int q = qrow0 + l15;
    const float inv = 1.0f / lS;
    ushort* op = Om + ((size_t)(b * S_ + q)) * D_ + h * HD_;
    #pragma unroll
    for (int dt = 0; dt < 8; ++dt) {
        ushort4 o;
        o.x = f2bf(oacc[dt][0] * inv);
        o.y = f2bf(oacc[dt][1] * inv);
        o.z = f2bf(oacc[dt][2] * inv);
        o.w = f2bf(oacc[dt][3] * inv);
        *reinterpret_cast<ushort4*>(op + dt * 16 + lg * 4) = o;
    }
}

extern "C" void kernel_launch(void* const* d_in, const int* in_sizes, int n_in,
                              void* d_out, int out_size, void* d_ws, size_t ws_size,
                              hipStream_t stream) {
    const float* x    = (const float*)d_in[0];
    const float* cosT = (const float*)d_in[1];
    const float* sinT = (const float*)d_in[2];
    const float* wq   = (const float*)d_in[3];
    const float* wk   = (const float*)d_in[4];
    const float* wv   = (const float*)d_in[5];
    const float* wo   = (const float*)d_in[6];
    float* out = (float*)d_out;

    char* ws = (char*)d_ws;
    const size_t szX = (size_t)B_ * S_ * D_ * 2;  // 16.78 MB
    const size_t szW = (size_t)D_ * D_ * 2;       // 8.39 MB
    ushort* xb   = (ushort*)(ws);
    ushort* wcat = (ushort*)(ws + szX);                 // [6144][2048] = wqT|wkT|wvT
    ushort* woT  = (ushort*)(ws + szX + 3 * szW);
    ushort* q0   = (ushort*)(ws + szX + 4 * szW);
    ushort* k0   = (ushort*)(ws + szX + 4 * szW + szX);
    ushort* v0   = (ushort*)(ws + szX + 4 * szW + 2 * szX);
    ushort* att  = xb;  // xb dead after QKV GEMM; reuse as attention output

    hipFuncSetAttribute(reinterpret_cast<const void*>(&gemm8<0>),
                        hipFuncAttributeMaxDynamicSharedMemorySize, 114688);
    hipFuncSetAttribute(reinterpret_cast<const void*>(&gemm8<1>),
                        hipFuncAttributeMaxDynamicSharedMemorySize, 98304);

    // weights transpose (z 0-3) + x cast (z 4-5), one dispatch
    prep_kernel<<<dim3(D_ / 64, D_ / 64, 6), 256, 0, stream>>>(
        wq, wk, wv, wo, wcat, wcat + (size_t)D_ * D_, wcat + 2 * (size_t)D_ * D_, woT,
        x, xb);

    // fused QKV (+RoPE in coalesced epilogue): M=4096, N=6144, BN=192 -> 512 wgs
    gemm8<0><<<512, 512, 114688, stream>>>(xb, wcat, q0, k0, v0, nullptr, cosT, sinT, 32);

    attn5<<<dim3(B_ * H_, S_ / 128), 512, 0, stream>>>(q0, k0, v0, att);

    // out projection: M=4096, N=2048, BN=128, per-wave 64x64 -> 256 wgs (one round)
    gemm8<1><<<256, 512, 98304, stream>>>(att, woT, nullptr, nullptr, nullptr, out,
                                          nullptr, nullptr, 16);
}

// Round 16
// 240.128 us; speedup vs baseline: 2.8227x; 1.0139x over previous
//
#include <hip/hip_runtime.h>
#include <hip/hip_bf16.h>

typedef short short8 __attribute__((ext_vector_type(8)));
typedef float f32x4 __attribute__((ext_vector_type(4)));
typedef int int4v __attribute__((ext_vector_type(4)));

#define B_ 2
#define S_ 2048
#define D_ 2048
#define H_ 16
#define HD_ 128
#define K_ 2048   // GEMM K (both projections)

#define GLL16(gp, lp) __builtin_amdgcn_global_load_lds( \
    (const __attribute__((address_space(1))) void*)(gp), \
    (__attribute__((address_space(3))) void*)(lp), 16, 0, 0)

__device__ inline ushort f2bf(float f) {
    union { float f; unsigned u; } v; v.f = f;
    unsigned r = v.u + 0x7FFFu + ((v.u >> 16) & 1u);
    return (ushort)(r >> 16);
}
__device__ inline float bf2f(ushort b) {
    union { unsigned u; float f; } v; v.u = ((unsigned)b) << 16;
    return v.f;
}

// rope 4 (even,odd) bf16 pairs in-register; cosp/sinp point at 4 consecutive f32
__device__ inline short8 rope8(short8 raw, const float* __restrict__ cosp,
                               const float* __restrict__ sinp) {
    float4 cs = *reinterpret_cast<const float4*>(cosp);
    float4 sn = *reinterpret_cast<const float4*>(sinp);
    const float* c = reinterpret_cast<const float*>(&cs);
    const float* s = reinterpret_cast<const float*>(&sn);
    short8 out;
    #pragma unroll
    for (int j = 0; j < 4; ++j) {
        float a = bf2f((ushort)raw[2 * j]), b = bf2f((ushort)raw[2 * j + 1]);
        out[2 * j]     = (short)f2bf(fmaf(a, c[j], -(b * s[j])));
        out[2 * j + 1] = (short)f2bf(fmaf(a, s[j], b * c[j]));
    }
    return out;
}

// z=0..3: w[K][N] f32 -> wT[N][K] bf16 via 64x64 LDS tile.
// z=4..5: fp32->bf16 cast of x (4 float4 chunks per block, stride 524288).
__global__ __launch_bounds__(256) void prep_kernel(
        const float* __restrict__ s0, const float* __restrict__ s1,
        const float* __restrict__ s2, const float* __restrict__ s3,
        ushort* __restrict__ d0, ushort* __restrict__ d1,
        ushort* __restrict__ d2, ushort* __restrict__ d3,
        const float* __restrict__ x, ushort* __restrict__ xb) {
    const int z = blockIdx.z;
    const int t = threadIdx.x;
    if (z >= 4) {
        const int lane = (((z - 4) * 1024 + blockIdx.y * 32 + blockIdx.x) << 8) + t;
        #pragma unroll
        for (int k = 0; k < 4; ++k) {
            int i = lane + k * 524288;
            float4 v = reinterpret_cast<const float4*>(x)[i];
            ushort4 o;
            o.x = f2bf(v.x); o.y = f2bf(v.y); o.z = f2bf(v.z); o.w = f2bf(v.w);
            reinterpret_cast<ushort4*>(xb)[i] = o;
        }
        return;
    }
    __shared__ ushort tile[64][72];
    const float* src = (z == 0) ? s0 : (z == 1) ? s1 : (z == 2) ? s2 : s3;
    ushort* dst = (z == 0) ? d0 : (z == 1) ? d1 : (z == 2) ? d2 : d3;
    const int bk = blockIdx.y * 64, bn = blockIdx.x * 64;
    #pragma unroll
    for (int it = 0; it < 4; ++it) {
        int id = t + it * 256;
        int row = id >> 4;
        int c4 = (id & 15) * 4;
        float4 v = *reinterpret_cast<const float4*>(&src[(size_t)(bk + row) * D_ + bn + c4]);
        ushort4 o; o.x = f2bf(v.x); o.y = f2bf(v.y); o.z = f2bf(v.z); o.w = f2bf(v.w);
        *reinterpret_cast<ushort4*>(&tile[row][c4]) = o;
    }
    __syncthreads();
    #pragma unroll
    for (int it = 0; it < 4; ++it) {
        int id = t + it * 256;
        int n = id >> 4;
        int c4 = (id & 15) * 4;
        ushort4 o;
        o.x = tile[c4 + 0][n]; o.y = tile[c4 + 1][n];
        o.z = tile[c4 + 2][n]; o.w = tile[c4 + 3][n];
        *reinterpret_cast<ushort4*>(&dst[(size_t)(bn + n) * D_ + bk + c4]) = o;
    }
}

// ===================== 256xBN 8-phase GEMM (T1+T2+T3+T4+T5) =====================
// MODE 0: BN=192, waves 2x4 (per-wave 128x48), N=6144 fused QKV -> bf16 (B,H,S,HD)
//         with RoPE fused in a coalesced LDS-bounce epilogue; grid 512 = 2 rounds.
// MODE 1: BN=128, waves 4x2 (per-wave 64x64), N=2048 -> f32; grid 256 = 1 round.
// Deep-lead stage order; counted vmcnt (oldest-7 rule) -> vmcnt(NBCH), tails drain 0.
// XCD-rectangle remap (r15): each XCD's co-resident blocks form a square-ish
// rectangle so per-XCD unique (A+B) footprint is minimized:
//   MODE 0: 8bm x 8bn per XCD -> per-XCD A 8.4MB + B 6.3MB (was 2x32: B=25MB)
//   MODE 1: 4bm x 8bn per XCD -> per-XCD A 4.2MB + B 4.2MB
// NOTE (r14 lesson): 2 blocks/CU + this tile size preserves k-slice lockstep.
#define BAR8() __builtin_amdgcn_s_barrier()
#define VMC0() asm volatile("s_waitcnt vmcnt(0)" ::: "memory")

template<int MODE>
__global__ __launch_bounds__(512, 2) void gemm8(const ushort* __restrict__ A,
        const ushort* __restrict__ Bt, ushort* __restrict__ q0, ushort* __restrict__ k0,
        ushort* __restrict__ v0, float* __restrict__ outf,
        const float* __restrict__ cosT, const float* __restrict__ sinT) {
    constexpr int NC      = (MODE == 0) ? 3 : 4;       // col frags per wave
    constexpr int NF      = (MODE == 0) ? 4 : 2;       // row frags per MM
    constexpr int ACCR    = NF * 2;                    // acc rows: 8 / 4
    constexpr int BN      = (MODE == 0) ? 192 : 128;
    constexpr int NBCH    = BN / 64;                   // B chunks per tile: 3 / 2
    constexpr int WCOLS   = (MODE == 0) ? 48 : 64;     // cols per wave
    constexpr int BBYTES  = BN * 128;                  // B bytes per buf
    constexpr int BSTRIDE = 32768 + BBYTES;            // 57344 / 49152

    extern __shared__ char smem[];
    const int tid = threadIdx.x, lane = tid & 63, wv = tid >> 6;
    const int wm = (MODE == 0) ? (wv >> 2) : (wv >> 1);
    const int wn = (MODE == 0) ? (wv & 3) : (wv & 1);
    const int l15 = lane & 15, lg = lane >> 4;
    // XCD-rectangle block remap (bijective; blocks i=x mod 8 land on XCD x)
    int bm, bn;
    {
        const int i = (int)blockIdx.x;
        const int x = i & 7, j = i >> 3;
        if (MODE == 0) {   // grid 512: rect 8bm x 8bn; rect grid 2r x 4c
            const int rr = x & 1, rc = x >> 1;
            bm = (rr * 8 + (j & 7)) * 256;
            bn = (rc * 8 + (j >> 3)) * BN;
        } else {           // grid 256: rect 4bm x 8bn; rect grid 4r x 2c
            const int rr = x >> 1, rc = x & 1;
            bm = (rr * 4 + (j & 3)) * 256;
            bn = (rc * 8 + (j >> 2)) * BN;
        }
    }

    f32x4 acc[ACCR][NC] = {};

    const int grl = wv * 8 + (lane >> 3);
    const int swc = (((lane & 7) ^ ((lane >> 3) & 7)) * 8);
    const ushort* Ag = A + (size_t)(bm + grl) * K_ + swc;
    const ushort* Bg = Bt + (size_t)(bn + grl) * K_ + swc;
    const size_t rowHA = (size_t)128 * K_;   // A half stride (rows)
    const size_t row64 = (size_t)64 * K_;    // 64-row chunk stride

#define VMCN() do { if (MODE == 0) asm volatile("s_waitcnt vmcnt(3)" ::: "memory"); \
                    else           asm volatile("s_waitcnt vmcnt(2)" ::: "memory"); } while (0)
#define STAGE_A(t, h) do { if ((t) < 32) { \
        const ushort* g = Ag + (size_t)(h) * rowHA + (size_t)(t) * 64; \
        char* l = smem + (((t) & 1) ? BSTRIDE : 0) + ((h) << 14) + (wv << 10); \
        GLL16(g, l); GLL16(g + row64, l + 8192); } } while (0)
#define STAGE_B(t, ch) do { if ((t) < 32) { \
        const ushort* g = Bg + (size_t)(ch) * row64 + (size_t)(t) * 64; \
        char* l = smem + (((t) & 1) ? BSTRIDE : 0) + 32768 + (ch) * 8192 + (wv << 10); \
        GLL16(g, l); } } while (0)
#define STAGE_B_ALL(t) do { _Pragma("unroll") \
        for (int ch = 0; ch < NBCH; ++ch) STAGE_B(t, ch); } while (0)

    const int colsw0 = (lg * 16) ^ ((l15 & 7) << 4);
    const int colsw1 = (64 + lg * 16) ^ ((l15 & 7) << 4);
    const char* abase0 = smem + wm * (NF * 4096);
    const char* bbase0 = smem + 32768;
    const char* abase1 = abase0 + BSTRIDE;
    const char* bbase1 = bbase0 + BSTRIDE;

#define LDA(ab, q, cs) do { _Pragma("unroll") for (int f = 0; f < NF; ++f) \
        a[f] = *reinterpret_cast<const short8*>((ab) + ((q) * (NF * 16) + f * 16 + l15) * 128 + (cs)); } while (0)
#define LDB(bb, cs) do { _Pragma("unroll") for (int c = 0; c < NC; ++c) { \
        const int rw = wn * WCOLS + c * 16; \
        b[c] = *reinterpret_cast<const short8*>((bb) + (rw >> 6) * 8192 + ((rw & 63) + l15) * 128 + (cs)); } } while (0)
#define MM(q) do { __builtin_amdgcn_s_setprio(1); \
        _Pragma("unroll") for (int f = 0; f < NF; ++f) \
        _Pragma("unroll") for (int c = 0; c < NC; ++c) \
            acc[(q) * NF + f][c] = __builtin_amdgcn_mfma_f32_16x16x32_bf16(a[f], b[c], acc[(q) * NF + f][c], 0, 0, 0); \
        __builtin_amdgcn_s_setprio(0); } while (0)

    // prologue: tile0 (A 4 + B NBCH) + tile1 B (NBCH) -> wait oldest 7
    STAGE_A(0, 0); STAGE_A(0, 1);
    STAGE_B_ALL(0);
    STAGE_B_ALL(1);
    VMCN();
    BAR8();

    for (int i = 0; i < 16; ++i) {
        const int t1 = 2 * i + 1, s0 = 2 * i + 2, s1 = 2 * i + 3;
        short8 a[NF], b[NC];
        // ph1: tile 2i (buf0); A(t1) into buf1-A (freed at prev ph8)
        LDB(bbase0, colsw0); LDA(abase0, 0, colsw0);
        STAGE_A(t1, 0);
        BAR8(); MM(0); BAR8();
        // ph2
        LDA(abase0, 1, colsw0);
        STAGE_A(t1, 1);
        BAR8(); MM(1); BAR8();
        // ph3: last B-read of tile 2i
        LDB(bbase0, colsw1); LDA(abase0, 0, colsw1);
        BAR8(); MM(0); BAR8();
        // ph4: B(s0) into buf0-B (freed at ph3); wait tile t1 resident (oldest 7)
        LDA(abase0, 1, colsw1);
        STAGE_B_ALL(s0);
        if (s0 < 32) VMCN(); else VMC0();
        BAR8(); MM(1); BAR8();
        // ph5: tile 2i+1 (buf1); A(s0) into buf0-A (freed at ph4)
        LDB(bbase1, colsw0); LDA(abase1, 0, colsw0);
        STAGE_A(s0, 0);
        BAR8(); MM(0); BAR8();
        // ph6
        LDA(abase1, 1, colsw0);
        STAGE_A(s0, 1);
        BAR8(); MM(1); BAR8();
        // ph7: last B-read of tile 2i+1
        LDB(bbase1, colsw1); LDA(abase1, 0, colsw1);
        BAR8(); MM(0); BAR8();
        // ph8: B(s1) into buf1-B (freed at ph7); wait tile s0 resident
        LDA(abase1, 1, colsw1);
        STAGE_B_ALL(s1);
        if (s1 < 32) VMCN(); else VMC0();
        BAR8(); MM(1); BAR8();
    }

    if (MODE == 0) {
        // ---- LDS-bounce epilogue with fused RoPE (conflict/coalesce-fixed) ----
        // eb[256][216] bf16 = 108 KB <= 112 KB. Row stride 432B = 27x16 (16B-aligned);
        // 432*lg = 16*lg mod 32 banks -> write pattern is a free 2-way.
        ushort* eb = (ushort*)smem;
        #pragma unroll
        for (int c = 0; c < NC; ++c)
            #pragma unroll
            for (int rf = 0; rf < ACCR; ++rf)
                #pragma unroll
                for (int j = 0; j < 4; ++j) {
                    int r = wm * 128 + rf * 16 + lg * 4 + j;
                    int cl = wn * WCOLS + c * 16 + l15;
                    eb[r * 216 + cl] = f2bf(acc[rf][c][j]);
                }
        __syncthreads();
        // store phase: 4 lanes per row, chunk-major. Each 4-lane group writes 64B
        // contiguous in one (h,s) row; groups never straddle head boundaries
        // (bn % 32 == 0, head boundary every 128 cols, group span 32 cols).
        const int rql = lane >> 2;       // 0..15 row within wave-pass
        const int cgrp = lane & 3;       // 16B chunk group
        #pragma unroll
        for (int p = 0; p < 2; ++p) {
            const int row = p * 128 + wv * 16 + rql;
            const int grow = bm + row;
            const int bb = grow >> 11, s = grow & (S_ - 1);
            const float* cr = cosT + (size_t)s * 64;
            const float* sr = sinT + (size_t)s * 64;
            const ushort* ebr = eb + row * 216;
            #pragma unroll
            for (int t = 0; t < 6; ++t) {
                const int coln = (cgrp + t * 4) * 8;     // 0..184, step 8 cols
                const int colg = bn + coln;
                const int seg = colg >> 11;
                const int h = (colg >> 7) & (H_ - 1), d = colg & (HD_ - 1);
                short8 v8 = *reinterpret_cast<const short8*>(ebr + coln);
                if (seg != 1)   // reference rotates q and v, not k
                    v8 = rope8(v8, cr + (d >> 1), sr + (d >> 1));
                ushort* segp = (seg == 0) ? q0 : ((seg == 1) ? k0 : v0);
                *reinterpret_cast<short8*>(segp + (((size_t)(bb * H_ + h)) * S_ + s) * HD_ + d) = v8;
            }
        }
    } else {
        #pragma unroll
        for (int rf = 0; rf < ACCR; ++rf)
            #pragma unroll
            for (int c = 0; c < NC; ++c)
                #pragma unroll
                for (int j = 0; j < 4; ++j) {
                    int row = bm + wm * (NF * 32) + rf * 16 + lg * 4 + j;
                    int col = bn + wn * WCOLS + c * 16 + l15;
                    outf[(size_t)row * D_ + col] = acc[rf][c][j];
                }
    }
#undef VMCN
#undef STAGE_A
#undef STAGE_B
#undef STAGE_B_ALL
#undef LDA
#undef LDB
#undef MM
}

// ============ causal flash attention v5: 8 waves, 128 q-rows/block ============
__global__ __launch_bounds__(512, 4) void attn5(const ushort* __restrict__ Qm,
        const ushort* __restrict__ Km, const ushort* __restrict__ Vm,
        ushort* __restrict__ Om) {
    __shared__ __align__(16) ushort Kb[2][64 * 128];   // swizzled [key][d], 16KB each
    __shared__ __align__(16) ushort Vt[2][128][72];    // [d][key]
    const int tid = threadIdx.x, lane = tid & 63, wv = tid >> 6;
    const int l15 = lane & 15, lg = lane >> 4;
    const int yy = (int)blockIdx.y;
    const int qt = (yy < 8) ? (15 - 2 * yy) : (2 * (yy - 8));
    const int bh = blockIdx.x;
    const size_t base = (size_t)bh * S_ * HD_;
    const int qrow0 = qt * 128 + wv * 16;
    const float C = 0.1275174f;            // (1/sqrt(128)) * log2(e)

    short8 qf[4];
    {
        const ushort* qp = Qm + base + (size_t)(qrow0 + l15) * HD_;
        #pragma unroll
        for (int c = 0; c < 4; ++c)
            qf[c] = *reinterpret_cast<const short8*>(qp + c * 32 + lg * 8);
    }
    f32x4 oacc[8] = {};
    float mS = -1e30f, lS = 0.f;
    const int ntiles = 2 * qt + 2;
    const int kmask0 = 2 * qt + (wv >> 2);

    {
        #pragma unroll
        for (int c = 0; c < 2; ++c) {
            int row = wv * 8 + c * 4 + (lane >> 4);
            GLL16(Km + base + (size_t)row * HD_ + (((lane & 15) ^ (row & 7)) << 3),
                  &Kb[0][wv * 1024 + c * 512]);
        }
        const ushort* vp = Vm + base + (size_t)lane * HD_ + wv * 16;
        #pragma unroll
        for (int cc = 0; cc < 2; ++cc) {
            int4v v = *reinterpret_cast<const int4v*>(vp + cc * 8);
            const ushort* e = reinterpret_cast<const ushort*>(&v);
            #pragma unroll
            for (int j = 0; j < 8; ++j) Vt[0][wv * 16 + cc * 8 + j][lane] = e[j];
        }
    }
    __syncthreads();

    int cur = 0;
    for (int kt = 0; kt < ntiles; ++kt) {
        const bool pfn = (kt + 1 < ntiles);
        int4v vr[2];
        if (pfn) {
            const int r0 = (kt + 1) * 64;
            #pragma unroll
            for (int c = 0; c < 2; ++c) {
                int row = wv * 8 + c * 4 + (lane >> 4);
                GLL16(Km + base + (size_t)(r0 + row) * HD_ + (((lane & 15) ^ (row & 7)) << 3),
                      &Kb[cur ^ 1][wv * 1024 + c * 512]);
            }
            const ushort* vp = Vm + base + (size_t)(r0 + lane) * HD_ + wv * 16;
            #pragma unroll
            for (int cc = 0; cc < 2; ++cc)
                vr[cc] = *reinterpret_cast<const int4v*>(vp + cc * 8);
        }
        f32x4 sacc[4] = {};
        const ushort* Kc = &Kb[cur][0];
        __builtin_amdgcn_s_setprio(1);
        #pragma unroll
        for (int ct = 0; ct < 4; ++ct) {
            const int row = ct * 16 + l15;
            const int sw = (row & 7) << 3;
            #pragma unroll
            for (int c = 0; c < 4; ++c) {
                short8 kf = *reinterpret_cast<const short8*>(
                    Kc + row * 128 + ((c * 32 + lg * 8) ^ sw));
                sacc[ct] = __builtin_amdgcn_mfma_f32_16x16x32_bf16(kf, qf[c], sacc[ct], 0, 0, 0);
            }
        }
        __builtin_amdgcn_s_setprio(0);

        float t16[16];
        #pragma unroll
        for (int ct = 0; ct < 4; ++ct)
            #pragma unroll
            for (int j = 0; j < 4; ++j) t16[ct * 4 + j] = sacc[ct][j];
        if (kt >= kmask0) {
            const int thr = qrow0 + l15 - kt * 64;
            #pragma unroll
            for (int ct = 0; ct < 4; ++ct)
                #pragma unroll
                for (int j = 0; j < 4; ++j)
                    if (ct * 16 + lg * 4 + j > thr) t16[ct * 4 + j] = -1e30f;
        }
        float mx[8];
        #pragma unroll
        for (int i = 0; i < 8; ++i) mx[i] = fmaxf(t16[i], t16[i + 8]);
        #pragma unroll
        for (int i = 0; i < 4; ++i) mx[i] = fmaxf(mx[i], mx[i + 4]);
        float m64 = fmaxf(fmaxf(mx[0], mx[1]), fmaxf(mx[2], mx[3]));
        m64 = fmaxf(m64, __shfl_xor(m64, 16));
        m64 = fmaxf(m64, __shfl_xor(m64, 32));
        if (!__all(m64 - mS <= 47.0f)) {
            float mnew = fmaxf(mS, m64);
            float corr = __builtin_amdgcn_exp2f((mS - mnew) * C);
            lS *= corr;
            #pragma unroll
            for (int dt = 0; dt < 8; ++dt)
                #pragma unroll
                for (int j = 0; j < 4; ++j) oacc[dt][j] *= corr;
            mS = mnew;
        }
        const float mcc = mS * C;
        float p[16];
        #pragma unroll
        for (int i = 0; i < 16; ++i)
            p[i] = __builtin_amdgcn_exp2f(fmaf(t16[i], C, -mcc));
        float sm[8];
        #pragma unroll
        for (int i = 0; i < 8; ++i) sm[i] = p[i] + p[i + 8];
        #pragma unroll
        for (int i = 0; i < 4; ++i) sm[i] = sm[i] + sm[i + 4];
        float psum = (sm[0] + sm[1]) + (sm[2] + sm[3]);
        psum += __shfl_xor(psum, 16);
        psum += __shfl_xor(psum, 32);
        lS += psum;

        unsigned dw[8];
        #pragma unroll
        for (int ct = 0; ct < 4; ++ct)
            #pragma unroll
            for (int u = 0; u < 2; ++u) {
                __hip_bfloat162 h2 = __float22bfloat162_rn(
                    float2{p[ct * 4 + 2 * u], p[ct * 4 + 2 * u + 1]});
                dw[ct * 2 + u] = *reinterpret_cast<unsigned*>(&h2);
            }
        #pragma unroll
        for (int c2 = 0; c2 < 2; ++c2) {
            int4v pfd;
            #pragma unroll
            for (int d = 0; d < 4; ++d) {
                int srcl = (lg & 1) * 32 + (d >> 1) * 16 + l15;
                int r0 = __shfl((int)dw[(2 * c2) * 2 + (d & 1)], srcl);
                int r1 = __shfl((int)dw[(2 * c2 + 1) * 2 + (d & 1)], srcl);
                pfd[d] = (lg & 2) ? r1 : r0;
            }
            short8 pf = *reinterpret_cast<short8*>(&pfd);
            __builtin_amdgcn_s_setprio(1);
            #pragma unroll
            for (int dt = 0; dt < 8; ++dt) {
                short8 vf = *reinterpret_cast<const short8*>(
                    &Vt[cur][dt * 16 + l15][c2 * 32 + lg * 8]);
                oacc[dt] = __builtin_amdgcn_mfma_f32_16x16x32_bf16(vf, pf, oacc[dt], 0, 0, 0);
            }
            __builtin_amdgcn_s_setprio(0);
        }
        if (pfn) {
            #pragma unroll
            for (int cc = 0; cc < 2; ++cc) {
                const ushort* e = reinterpret_cast<const ushort*>(&vr[cc]);
                #pragma unroll
                for (int j = 0; j < 8; ++j) Vt[cur ^ 1][wv * 16 + cc * 8 + j][lane] = e[j];
            }
        }
        __syncthreads();
        cur ^= 1;
    }
    const int b = bh >> 4, h = bh & (H_ - 1);
    const int q = qrow0 + l15;
    const float inv = 1.0f / lS;
    ushort* op = Om + ((size_t)(b * S_ + q)) * D_ + h * HD_;
    #pragma unroll
    for (int dt = 0; dt < 8; ++dt) {
        ushort4 o;
        o.x = f2bf(oacc[dt][0] * inv);
        o.y = f2bf(oacc[dt][1] * inv);
        o.z = f2bf(oacc[dt][2] * inv);
        o.w = f2bf(oacc[dt][3] * inv);
        *reinterpret_cast<ushort4*>(op + dt * 16 + lg * 4) = o;
    }
}

extern "C" void kernel_launch(void* const* d_in, const int* in_sizes, int n_in,
                              void* d_out, int out_size, void* d_ws, size_t ws_size,
                              hipStream_t stream) {
    const float* x    = (const float*)d_in[0];
    const float* cosT = (const float*)d_in[1];
    const float* sinT = (const float*)d_in[2];
    const float* wq   = (const float*)d_in[3];
    const float* wk   = (const float*)d_in[4];
    const float* wv   = (const float*)d_in[5];
    const float* wo   = (const float*)d_in[6];
    float* out = (float*)d_out;

    char* ws = (char*)d_ws;
    const size_t szX = (size_t)B_ * S_ * D_ * 2;  // 16.78 MB
    const size_t szW = (size_t)D_ * D_ * 2;       // 8.39 MB
    ushort* xb   = (ushort*)(ws);
    ushort* wcat = (ushort*)(ws + szX);                 // [6144][2048] = wqT|wkT|wvT
    ushort* woT  = (ushort*)(ws + szX + 3 * szW);
    ushort* q0   = (ushort*)(ws + szX + 4 * szW);
    ushort* k0   = (ushort*)(ws + szX + 4 * szW + szX);
    ushort* v0   = (ushort*)(ws + szX + 4 * szW + 2 * szX);
    ushort* att  = xb;  // xb dead after QKV GEMM; reuse as attention output

    hipFuncSetAttribute(reinterpret_cast<const void*>(&gemm8<0>),
                        hipFuncAttributeMaxDynamicSharedMemorySize, 114688);
    hipFuncSetAttribute(reinterpret_cast<const void*>(&gemm8<1>),
                        hipFuncAttributeMaxDynamicSharedMemorySize, 98304);

    // weights transpose (z 0-3) + x cast (z 4-5), one dispatch
    prep_kernel<<<dim3(D_ / 64, D_ / 64, 6), 256, 0, stream>>>(
        wq, wk, wv, wo, wcat, wcat + (size_t)D_ * D_, wcat + 2 * (size_t)D_ * D_, woT,
        x, xb);

    // fused QKV (+RoPE in coalesced epilogue): M=4096, N=6144, BN=192 -> 512 wgs
    gemm8<0><<<512, 512, 114688, stream>>>(xb, wcat, q0, k0, v0, nullptr, cosT, sinT);

    attn5<<<dim3(B_ * H_, S_ / 128), 512, 0, stream>>>(q0, k0, v0, att);

    // out projection: M=4096, N=2048, BN=128, per-wave 64x64 -> 256 wgs (one round)
    gemm8<1><<<256, 512, 98304, stream>>>(att, woT, nullptr, nullptr, nullptr, out,
                                          nullptr, nullptr);
}